// Round 9
// baseline (831.790 us; speedup 1.0000x reference)
//
#include <hip/hip_runtime.h>
#include <hip/hip_bf16.h>

typedef unsigned short u16;
typedef __attribute__((ext_vector_type(8))) __bf16 bf16x8;
typedef __attribute__((ext_vector_type(8))) u16 u16x8;
typedef __attribute__((ext_vector_type(4))) u16 u16x4;
typedef __attribute__((ext_vector_type(4))) float floatx4;

#define C_     512
#define NC_    12
#define BT_    1024
#define SEQ_   21
#define M_REG  21504
#define M_GAT  12288

__device__ __forceinline__ float bf2f(u16 u) {
  unsigned int v = ((unsigned int)u) << 16;
  float f; __builtin_memcpy(&f, &v, 4); return f;
}
__device__ __forceinline__ u16 f2bf(float f) {
  unsigned int b; __builtin_memcpy(&b, &f, 4);
  unsigned int r = (b + 0x7FFFu + ((b >> 16) & 1u)) >> 16;
  return (u16)r;
}
__device__ __forceinline__ float ldf(const void* p, size_t i, int f32) {
  return f32 ? ((const float*)p)[i] : bf2f(((const u16*)p)[i]);
}
__device__ __forceinline__ u16 ldbf(const void* p, size_t i, int f32) {
  return f32 ? f2bf(((const float*)p)[i]) : ((const u16*)p)[i];
}
__device__ __forceinline__ void stout(void* p, size_t i, float v, int f32) {
  if (f32) ((float*)p)[i] = v; else ((u16*)p)[i] = f2bf(v);
}

typedef __attribute__((address_space(1))) unsigned int as1_u32;
typedef __attribute__((address_space(3))) unsigned int as3_u32;
__device__ __forceinline__ void gl2lds16(const void* g, void* l) {
  __builtin_amdgcn_global_load_lds((const as1_u32*)g, (as3_u32*)l, 16, 0, 0);
}

__global__ void sent_k(float* __restrict__ o, float val) {
  const int i = blockIdx.x * 256 + threadIdx.x;
  if (i < 16384) o[i] = val;
}

// block 0: dtype detect; blocks 1..: zero the stats region
__global__ void detect_k(const u16* __restrict__ x, int* __restrict__ flag,
                         float* __restrict__ stats, int nstat) {
  if (blockIdx.x == 0) {
    __shared__ int cnt;
    if (threadIdx.x == 0) cnt = 0;
    __syncthreads();
    int bad = 0;
    for (int i = threadIdx.x; i < 4096; i += 256) {
      const float v = bf2f(x[i]);
      const float a = fabsf(v);
      if (!(a <= 1e4f)) bad++;
      else if (a > 0.f && a < 1e-35f) bad++;
    }
    atomicAdd(&cnt, bad);
    __syncthreads();
    if (threadIdx.x == 0) *flag = (cnt > 400) ? 1 : 0;
  } else {
    const int id = (blockIdx.x - 1) * 256 + threadIdx.x;
    if (id < nstat) stats[id] = 0.f;
  }
}

__global__ void transpose512(const void* __restrict__ rW, const void* __restrict__ cW,
                             const void* __restrict__ gW, u16* __restrict__ oR,
                             u16* __restrict__ oC, u16* __restrict__ oG,
                             const int* __restrict__ flagp) {
  const int f32 = *flagp;
  const int z = blockIdx.z;
  const void* src; u16* dst; size_t sofs = 0;
  if (z < 4)       { src = rW; sofs = (size_t)z*262144;     dst = oR + (size_t)z*262144; }
  else if (z < 16) { src = cW; sofs = (size_t)(z-4)*262144; dst = oC + (size_t)(z-4)*262144; }
  else             { src = gW;                              dst = oG; }
  __shared__ u16 t[32][33];
  const int tx = threadIdx.x;
  const int cy = blockIdx.y * 32, dx = blockIdx.x * 32;
  for (int i = threadIdx.y; i < 32; i += 8)
    t[i][tx] = ldbf(src, sofs + (size_t)(cy + i)*512 + dx + tx, f32);
  __syncthreads();
  for (int i = threadIdx.y; i < 32; i += 8)
    dst[(size_t)(dx + i)*512 + cy + tx] = t[tx][i];
}

// MODE 0: regions (A = x, maybe fp32; z = region). MODE 1: classes (zeff = n0+z).
// MODE 2: GAT projection (no bias/stats).  [R7-proven structure: BK=32]
template<int MODE>
__global__ __launch_bounds__(256)
void gemm_k(const void* __restrict__ Abase, const u16* __restrict__ Wtb,
            const void* __restrict__ biasb, u16* __restrict__ outb,
            float* __restrict__ ssumb, float* __restrict__ ssqb,
            const int* __restrict__ flagp, int pk, int n0)
{
  const int f32 = *flagp;
  const int z = blockIdx.z;
  const int zeff = (MODE == 1) ? (n0 + z) : z;
  const void* A = Abase;
  if (MODE == 1) A = (const void*)((const u16*)Abase +
        (size_t)((pk >> (zeff * 2)) & 3) * ((size_t)M_REG * C_));
  const u16* Wt = Wtb + (size_t)zeff * C_ * C_;
  u16* Out = outb + (size_t)z * (size_t)M_REG * C_;

  __shared__ __align__(16) u16 smem[64 * 132];   // 16896 B
  u16* As = smem;
  u16* Bs = smem + 4096;

  const int tid  = threadIdx.x;
  const int w    = tid >> 6;
  const int lane = tid & 63;
  const int wm   = w >> 1, wn = w & 1;
  const int r16  = lane & 15, q = lane >> 4;

  const int band = (MODE == 2) ? 12 : 21;
  const int lin  = blockIdx.x;
  const int xcd  = lin & 7;
  const int idx  = lin >> 3;
  const int mi   = xcd * band + idx % band;
  const int ni   = idx / band;
  const int m0   = mi * 128;
  const int nn0  = ni * 128;

  const int sub = lane >> 2;
  const int kq  = (lane & 3) * 8;
  const int am0 = m0 + w*32 + sub;
  const int am1 = am0 + 16;
  long ga0, ga1;
  if (MODE == 0) {
    const int roff = (pk >> (z * 8)) & 0xFF;
    int q21 = am0 / 21; int rm = am0 - q21*21;
    ga0 = (long)q21*49 + roff + rm;
    q21 = am1 / 21; rm = am1 - q21*21;
    ga1 = (long)q21*49 + roff + rm;
  } else { ga0 = am0; ga1 = am1; }
  const size_t aOff0 = (size_t)ga0 * C_ + kq;
  const size_t aOff1 = (size_t)ga1 * C_ + kq;
  const u16* bSrc0 = Wt + (size_t)(nn0 + w*32 + sub) * C_ + kq;
  const u16* bSrc1 = bSrc0 + (size_t)16 * C_;
  u16* aDstW0 = &As[(w*32 +  0) * 32];
  u16* aDstW1 = &As[(w*32 + 16) * 32];
  u16* bDstW0 = &Bs[(w*32 +  0) * 32];
  u16* bDstW1 = &Bs[(w*32 + 16) * 32];
  u16x8* aLds0 = (u16x8*)&As[(w*32 + sub +  0) * 32 + kq];
  u16x8* aLds1 = (u16x8*)&As[(w*32 + sub + 16) * 32 + kq];

  floatx4 acc[4][4];
  #pragma unroll
  for (int i = 0; i < 4; i++)
    #pragma unroll
    for (int j = 0; j < 4; j++)
      acc[i][j] = (floatx4){0.f, 0.f, 0.f, 0.f};

  for (int kk = 0; kk < C_; kk += 32) {
    if (MODE == 0 && f32) {
      const float* p0 = (const float*)A + aOff0 + kk;
      const float* p1 = (const float*)A + aOff1 + kk;
      const floatx4 f00 = *(const floatx4*)p0;
      const floatx4 f01 = *(const floatx4*)(p0 + 4);
      const floatx4 f10 = *(const floatx4*)p1;
      const floatx4 f11 = *(const floatx4*)(p1 + 4);
      u16x8 va0, va1;
      #pragma unroll
      for (int j = 0; j < 4; j++) {
        va0[j] = f2bf(f00[j]); va0[4+j] = f2bf(f01[j]);
        va1[j] = f2bf(f10[j]); va1[4+j] = f2bf(f11[j]);
      }
      __syncthreads();
      gl2lds16(bSrc0, bDstW0); gl2lds16(bSrc1, bDstW1);
      *aLds0 = va0; *aLds1 = va1;
      __syncthreads();
    } else {
      __syncthreads();
      gl2lds16((const u16*)A + aOff0 + kk, aDstW0);
      gl2lds16((const u16*)A + aOff1 + kk, aDstW1);
      gl2lds16(bSrc0, bDstW0);
      gl2lds16(bSrc1, bDstW1);
      __syncthreads();
    }
    bSrc0 += 32; bSrc1 += 32;
    bf16x8 av[4], bv[4];
    #pragma unroll
    for (int mt = 0; mt < 4; mt++)
      av[mt] = *(const bf16x8*)&As[(wm*64 + mt*16 + r16)*32 + q*8];
    #pragma unroll
    for (int nt = 0; nt < 4; nt++)
      bv[nt] = *(const bf16x8*)&Bs[(wn*64 + nt*16 + r16)*32 + q*8];
    #pragma unroll
    for (int mt = 0; mt < 4; mt++)
      #pragma unroll
      for (int nt = 0; nt < 4; nt++)
        acc[mt][nt] = __builtin_amdgcn_mfma_f32_16x16x32_bf16(av[mt], bv[nt], acc[mt][nt], 0, 0, 0);
  }

  // ---- epilogue: bias+stats in regs, LDS transpose, coalesced 16B stores ----
  #pragma unroll
  for (int rh = 0; rh < 2; rh++) {
    __syncthreads();
    if (wm == rh) {
      #pragma unroll
      for (int nt = 0; nt < 4; nt++) {
        const int lcol = wn*64 + nt*16 + r16;
        float bvv = 0.f;
        if (MODE != 2) bvv = ldf(biasb, (size_t)zeff * C_ + nn0 + lcol, f32);
        float s = 0.f, s2 = 0.f;
        #pragma unroll
        for (int mt = 0; mt < 4; mt++) {
          #pragma unroll
          for (int p = 0; p < 4; p++) {
            const float v = acc[mt][nt][p] + bvv;
            s += v; s2 += v*v;
            smem[(mt*16 + q*4 + p)*132 + lcol] = f2bf(v);
          }
        }
        if (MODE != 2) {
          s  += __shfl_xor(s, 16);  s  += __shfl_xor(s, 32);
          s2 += __shfl_xor(s2, 16); s2 += __shfl_xor(s2, 32);
          if (q == 0) {
            atomicAdd(&ssumb[(size_t)zeff * C_ + nn0 + lcol], s);
            atomicAdd(&ssqb [(size_t)zeff * C_ + nn0 + lcol], s2);
          }
        }
      }
    }
    __syncthreads();
    #pragma unroll
    for (int rr = 0; rr < 4; rr++) {
      const int rl = rr*16 + (tid >> 4);
      const int cc = (tid & 15) * 8;
      const u16x8 vv = *(const u16x8*)&smem[rl*132 + cc];
      *(u16x8*)&Out[(size_t)(m0 + rh*64 + rl) * C_ + nn0 + cc] = vv;  // cacheable: L3-resident chunks
    }
  }
}

// ---- region BN+relu (in-place) + seq-mean -> hbar; 8 channels/lane ----
__global__ void bn_region(u16* __restrict__ h, float* __restrict__ hbar,
                          const void* __restrict__ gamma, const void* __restrict__ beta,
                          const float* __restrict__ rsum, const float* __restrict__ rsq,
                          const int* __restrict__ flagp) {
  const int f32 = *flagp;
  const int gid  = blockIdx.x;
  const int r    = gid >> 8;
  const int bt   = ((gid & 255) << 2) + (threadIdx.x >> 6);
  const int lane = threadIdx.x & 63;
  const int d0   = lane * 8;
  const int rd   = r*512 + d0;
  float sc[8], sh[8], accv[8];
  #pragma unroll
  for (int j = 0; j < 8; j++) {
    const float mean = rsum[rd+j] * (1.f/21504.f);
    const float var  = fmaxf(rsq[rd+j] * (1.f/21504.f) - mean*mean, 0.f);
    sc[j] = ldf(gamma, rd+j, f32) * rsqrtf(var + 1e-5f);
    sh[j] = ldf(beta,  rd+j, f32) - mean * sc[j];
    accv[j] = 0.f;
  }
  const size_t base = ((size_t)r * M_REG + (size_t)bt * SEQ_) * C_ + d0;
  #pragma unroll
  for (int s = 0; s < SEQ_; s++) {
    u16x8 vv = *(u16x8*)&h[base + (size_t)s*C_];
    #pragma unroll
    for (int j = 0; j < 8; j++) {
      float v = fmaxf(sc[j] * bf2f(vv[j]) + sh[j], 0.f);
      vv[j] = f2bf(v);
      accv[j] += v;
    }
    *(u16x8*)&h[base + (size_t)s*C_] = vv;
  }
  float* hb = &hbar[((size_t)r * BT_ + bt) * C_ + d0];
  #pragma unroll
  for (int j = 0; j < 8; j++) hb[j] = accv[j] * (1.f/21.f);
}

// ---- prediction heads: wave-parallel dot products ----
__global__ void preds_k(const float* __restrict__ hbar,
                        const void* __restrict__ upW,  const void* __restrict__ upB,
                        const void* __restrict__ midW, const void* __restrict__ midB,
                        const void* __restrict__ d1W,  const void* __restrict__ d1B,
                        const void* __restrict__ d2W,  const void* __restrict__ d2B,
                        void* __restrict__ dout, const int* __restrict__ flagp) {
  const int f32 = *flagp;
  const int bt = blockIdx.x;
  __shared__ float hl[4][512];
  for (int i = threadIdx.x; i < 2048; i += 256)
    hl[i >> 9][i & 511] = hbar[((size_t)(i >> 9) * BT_ + bt) * C_ + (i & 511)];
  __syncthreads();
  const int w = threadIdx.x >> 6, lane = threadIdx.x & 63;
  for (int j = w; j < 42; j += 4) {
    int r, wdt, col; const void *W, *Bv; size_t oofs;
    if (j < 16)      { r=0; W=upW;  Bv=upB;  wdt=16; col=j;    oofs = (size_t)bt*16 + col; }
    else if (j < 18) { r=1; W=midW; Bv=midB; wdt=2;  col=j-16; oofs = 16384 + (size_t)bt*2 + col; }
    else if (j < 26) { r=2; W=d1W;  Bv=d1B;  wdt=8;  col=j-18; oofs = 18432 + (size_t)bt*8 + col; }
    else             { r=3; W=d2W;  Bv=d2B;  wdt=16; col=j-26; oofs = 26624 + (size_t)bt*16 + col; }
    float acc = 0.f;
    #pragma unroll
    for (int e = 0; e < 8; e++) {
      const int d = lane*8 + e;
      acc += hl[r][d] * ldf(W, (size_t)d*wdt + col, f32);
    }
    #pragma unroll
    for (int off = 32; off; off >>= 1) acc += __shfl_xor(acc, off);
    if (lane == 0) stout(dout, oofs, acc + ldf(Bv, col, f32), f32);
  }
}

// ---- class BN+relu + seq-mean -> f_v; 8 channels/lane ----
__global__ void bn_class_mean(const u16* __restrict__ ypre, u16* __restrict__ fv,
                              const void* __restrict__ gamma, const void* __restrict__ beta,
                              const float* __restrict__ csum, const float* __restrict__ csq,
                              const int* __restrict__ flagp, int n0) {
  const int f32 = *flagp;
  const int gid  = blockIdx.x;
  const int zz   = gid >> 8;
  const int bt   = ((gid & 255) << 2) + (threadIdx.x >> 6);
  const int lane = threadIdx.x & 63;
  const int d0   = lane * 8;
  const int n    = n0 + zz;
  const int nd   = n*512 + d0;
  float sc[8], sh[8], accv[8];
  #pragma unroll
  for (int j = 0; j < 8; j++) {
    const float mean = csum[nd+j] * (1.f/21504.f);
    const float var  = fmaxf(csq[nd+j] * (1.f/21504.f) - mean*mean, 0.f);
    sc[j] = ldf(gamma, nd+j, f32) * rsqrtf(var + 1e-5f);
    sh[j] = ldf(beta,  nd+j, f32) - mean * sc[j];
    accv[j] = 0.f;
  }
  const size_t base = ((size_t)zz * M_REG + (size_t)bt * SEQ_) * C_ + d0;
  #pragma unroll
  for (int s = 0; s < SEQ_; s++) {
    const u16x8 vv = *(const u16x8*)&ypre[base + (size_t)s*C_];
    #pragma unroll
    for (int j = 0; j < 8; j++)
      accv[j] += fmaxf(sc[j] * bf2f(vv[j]) + sh[j], 0.f);
  }
  u16x8 ov;
  #pragma unroll
  for (int j = 0; j < 8; j++) ov[j] = f2bf(accv[j] * (1.f/21.f));
  *(u16x8*)&fv[((size_t)bt * NC_ + n) * C_ + d0] = ov;
}

__global__ __launch_bounds__(256)
void gat_k(const u16* __restrict__ hg, const u16* __restrict__ fv,
           const void* __restrict__ al, const void* __restrict__ ar,
           const void* __restrict__ adj_mask, float* __restrict__ g,
           const int* __restrict__ flagp) {
  const int f32 = *flagp;
  const int bt = blockIdx.x;
  __shared__ float hl[12][512];
  __shared__ float alv[12], arv[12], attn[12][12];
  const u16* hgb = hg + (size_t)bt * NC_ * C_;
  for (int i = threadIdx.x * 8; i < 6144; i += 2048) {
    const u16x8 vv = *(const u16x8*)&hgb[i];
    const int ii = i >> 9, cc = i & 511;
    #pragma unroll
    for (int e = 0; e < 8; e++) hl[ii][cc + e] = bf2f(vv[e]);
  }
  __syncthreads();
  const int w = threadIdx.x >> 6, lane = threadIdx.x & 63;
  for (int i = w; i < 12; i += 4) {
    float pa = 0.f, pr = 0.f;
    #pragma unroll
    for (int jj = 0; jj < 8; jj++) {
      const int c = lane*8 + jj;
      const float hv = hl[i][c];
      pa += hv * ldf(al, c, f32);
      pr += hv * ldf(ar, c, f32);
    }
    #pragma unroll
    for (int off = 32; off; off >>= 1) { pa += __shfl_xor(pa, off); pr += __shfl_xor(pr, off); }
    if (lane == 0) { alv[i] = pa; arv[i] = pr; }
  }
  __syncthreads();
  if (threadIdx.x < 12) {
    const unsigned AM[12] = {0xFE8,0xFE8,0xFE8,0xFF7,0xFE8,0x1DF,
                             0xE3F,0xE3F,0xE3F,0x1DF,0x1DF,0x1DF};
    const int i = threadIdx.x;
    float row[12]; float mx = -1e30f;
    #pragma unroll
    for (int jx = 0; jx < 12; jx++) {
      const float maskv = ldf(adj_mask, (size_t)bt*144 + i*12 + jx, f32);
      const float adjv = (float)((AM[i] >> jx) & 1u) * maskv + (i == jx ? 1.f : 0.f);
      float e;
      if (adjv > 0.1f) {
        const float t = alv[i] + arv[jx];
        e = t > 0.f ? t : 0.2f * t;
      } else e = -1e9f;
      row[jx] = e; mx = fmaxf(mx, e);
    }
    float den = 0.f;
    #pragma unroll
    for (int jx = 0; jx < 12; jx++) { const float ex = __expf(row[jx] - mx); row[jx] = ex; den += ex; }
    const float inv = 1.f / den;
    #pragma unroll
    for (int jx = 0; jx < 12; jx++) attn[i][jx] = row[jx] * inv;
  }
  __syncthreads();
  const u16* fvb = fv + (size_t)bt * NC_ * C_;
  float* gb = g + (size_t)bt * NC_ * C_;
  for (int o = threadIdx.x; o < 6144; o += 256) {
    const int i = o >> 9, c = o & 511;
    float acc = bf2f(fvb[o]);
    #pragma unroll
    for (int jx = 0; jx < 12; jx++) acc += attn[i][jx] * hl[jx][c];
    gb[o] = acc;
  }
}

__global__ void tconv_k(float* __restrict__ g, const void* __restrict__ tw,
                        const void* __restrict__ tb, float* __restrict__ tsum,
                        float* __restrict__ tsq, const int* __restrict__ flagp) {
  const int f32 = *flagp;
  const int id = blockIdx.x * 256 + threadIdx.x;
  const int c = id & 511;
  const int n = (id >> 9) % 12;
  const int b = id / 6144;
  float wk[5];
  #pragma unroll
  for (int k = 0; k < 5; k++) wk[k] = ldf(tw, (size_t)(n*512 + c)*5 + k, f32);
  const float bias = ldf(tb, n*512 + c, f32);
  float xv[36];
  xv[0] = xv[1] = xv[34] = xv[35] = 0.f;
  const size_t base = ((size_t)b * 32 * NC_ + n) * C_ + c;
  #pragma unroll
  for (int t = 0; t < 32; t++) xv[t + 2] = g[base + (size_t)t * 6144];
  float s = 0.f, s2 = 0.f;
  float ov[32];
  #pragma unroll
  for (int t = 0; t < 32; t++) {
    float v = bias;
    #pragma unroll
    for (int k = 0; k < 5; k++) v += wk[k] * xv[t + k];
    ov[t] = v; s += v; s2 += v*v;
  }
  #pragma unroll
  for (int t = 0; t < 32; t++) g[base + (size_t)t * 6144] = ov[t];
  #pragma unroll
  for (int off = 32; off; off >>= 1) { s += __shfl_xor(s, off); s2 += __shfl_xor(s2, off); }
  if ((threadIdx.x & 63) == 0) { atomicAdd(&tsum[n], s); atomicAdd(&tsq[n], s2); }
}

// ---- final BN+relu -> d_out; 4 elems/thread ----
__global__ void bn_t(const float* __restrict__ v, void* __restrict__ outp,
                     const void* __restrict__ tg, const void* __restrict__ tb2,
                     const float* __restrict__ tsum, const float* __restrict__ tsq,
                     const int* __restrict__ flagp) {
  const int f32 = *flagp;
  const size_t id4 = (size_t)blockIdx.x * 256 + threadIdx.x;
  const int n = (int)((id4 >> 7) % 12);
  const float mean = tsum[n] * (1.f/524288.f);
  const float var  = fmaxf(tsq[n] * (1.f/524288.f) - mean*mean, 0.f);
  const float sc = ldf(tg, n, f32) * rsqrtf(var + 1e-5f);
  const float sh = ldf(tb2, n, f32) - mean * sc;
  const floatx4 vv = *(const floatx4*)&v[id4 * 4];
  if (f32) {
    floatx4 ov;
    #pragma unroll
    for (int e = 0; e < 4; e++) ov[e] = fmaxf(sc * vv[e] + sh, 0.f);
    *(floatx4*)&((float*)outp)[43008 + id4*4] = ov;
  } else {
    u16x4 ov;
    #pragma unroll
    for (int e = 0; e < 4; e++) ov[e] = f2bf(fmaxf(sc * vv[e] + sh, 0.f));
    *(u16x4*)&((u16*)outp)[43008 + id4*4] = ov;
  }
}

static constexpr size_t OFF_FLAG = 0;
static constexpr size_t OFF_STAT = 64;
static constexpr int    STAT_N   = 2048+2048+6144+6144+12+12;
static constexpr size_t OFF_WTR  = 65792;
static constexpr size_t OFF_WTC  = OFF_WTR + (size_t)4*512*512*2;
static constexpr size_t OFF_WTG  = OFF_WTC + (size_t)12*512*512*2;
static constexpr size_t OFF_H    = OFF_WTG + (size_t)512*512*2;
static constexpr size_t OFF_HBAR = OFF_H + (size_t)4*M_REG*C_*2;
static constexpr size_t OFF_FV   = OFF_HBAR + (size_t)4*BT_*C_*4;
static constexpr size_t OFF_AREN = OFF_FV + (size_t)M_GAT*C_*2;
static constexpr size_t YPRE_B   = (size_t)M_REG * C_ * 2;
static constexpr size_t NEEDED   = OFF_AREN + YPRE_B;

extern "C" void kernel_launch(void* const* d_in, const int* in_sizes, int n_in,
                              void* d_out, int out_size, void* d_ws, size_t ws_size,
                              hipStream_t stream) {
  const u16* x        = (const u16*)d_in[0];
  const void* adj_m   = d_in[1];
  const void* region_W= d_in[2];
  const void* region_b= d_in[3];
  const void* region_g= d_in[4];
  const void* region_be=d_in[5];
  const void* upW  = d_in[6];   const void* upB  = d_in[7];
  const void* midW = d_in[8];   const void* midB = d_in[9];
  const void* d1W  = d_in[10];  const void* d1B  = d_in[11];
  const void* d2W  = d_in[12];  const void* d2B  = d_in[13];
  const void* class_W = d_in[14];
  const void* class_b = d_in[15];
  const void* class_g = d_in[16];
  const void* class_be= d_in[17];
  const void* gat_W   = d_in[18];
  const void* gat_al  = d_in[19];
  const void* gat_ar  = d_in[20];
  const void* tconv_W = d_in[21];
  const void* tconv_b = d_in[22];
  const void* tbn_g   = d_in[23];
  const void* tbn_be  = d_in[24];

  char* ws = (char*)d_ws;
  int*   flagp = (int*)(ws + OFF_FLAG);
  float* rsum = (float*)(ws + OFF_STAT);
  float* rsq  = rsum + 2048;
  float* csum = rsq  + 2048;
  float* csq  = csum + 6144;
  float* tsum = csq  + 6144;
  float* tsq  = tsum + 12;
  u16*   WtR  = (u16*)(ws + OFF_WTR);
  u16*   WtC  = (u16*)(ws + OFF_WTC);
  u16*   WtG  = (u16*)(ws + OFF_WTG);
  u16*   h    = (u16*)(ws + OFF_H);
  float* hbar = (float*)(ws + OFF_HBAR);
  u16*   fv   = (u16*)(ws + OFF_FV);
  u16*   ypre = (u16*)(ws + OFF_AREN);
  u16*   hg   = (u16*)(ws + OFF_AREN);
  float* g    = (float*)(ws + OFF_H);

  int errStage = 0, errCode = 0;
  (void)hipGetLastError();
  #define CK(s) do { hipError_t e_ = hipGetLastError(); \
      if (e_ != hipSuccess && errStage == 0) { errStage = (s); errCode = (int)e_; } } while(0)

  sent_k<<<64, 256, 0, stream>>>((float*)d_out, 50.f); CK(12);

  if (ws_size < NEEDED) {
    int mb = (int)(ws_size >> 20); if (mb > 999) mb = 999;
    sent_k<<<64, 256, 0, stream>>>((float*)d_out, 13000.f + (float)mb);
    return;
  }

  // classes per chunk: cap at 6 so each ypre chunk (132 MB) fits in the 256 MB L3,
  // letting bn_class_mean read from cache instead of HBM.
  int nch = (int)((ws_size - OFF_AREN) / YPRE_B);
  if (nch > 6) nch = 6;
  if (nch < 1) nch = 1;

  const int ROFFPACK = 0 | (14 << 8) | (28 << 16) | (28 << 24);
  const int SELPACK  = (1 << 6) | (3 << 10) | (2 << 12) | (2 << 14) |
                       (2 << 16) | (3 << 18) | (3 << 20) | (3 << 22);

  detect_k<<<1 + (STAT_N + 255)/256, 256, 0, stream>>>(x, flagp, rsum, STAT_N); CK(1);
  transpose512<<<dim3(16,16,17), dim3(32,8), 0, stream>>>(
      region_W, class_W, gat_W, WtR, WtC, WtG, flagp);               CK(2);

  gemm_k<0><<<dim3(672,1,4), 256, 0, stream>>>(
      x, WtR, region_b, h, rsum, rsq, flagp, ROFFPACK, 0);           CK(3);
  bn_region<<<1024, 256, 0, stream>>>(h, hbar, region_g, region_be,
      rsum, rsq, flagp);                                             CK(4);
  preds_k<<<1024, 256, 0, stream>>>(hbar, upW,upB, midW,midB,
      d1W,d1B, d2W,d2B, d_out, flagp);                               CK(5);

  for (int n0 = 0; n0 < 12; n0 += nch) {
    const int zc = (12 - n0) < nch ? (12 - n0) : nch;
    gemm_k<1><<<dim3(672,1,zc), 256, 0, stream>>>(
        h, WtC, class_b, ypre, csum, csq, flagp, SELPACK, n0);       CK(6);
    bn_class_mean<<<zc*256, 256, 0, stream>>>(ypre, fv, class_g, class_be,
        csum, csq, flagp, n0);                                       CK(7);
  }

  gemm_k<2><<<dim3(384,1,1), 256, 0, stream>>>(
      fv, WtG, nullptr, hg, nullptr, nullptr, flagp, 0, 0);          CK(8);
  gat_k<<<1024, 256, 0, stream>>>(hg, fv, gat_al, gat_ar, adj_m, g, flagp); CK(9);
  tconv_k<<<768, 256, 0, stream>>>(g, tconv_W, tconv_b, tsum, tsq, flagp);  CK(10);
  bn_t<<<6144, 256, 0, stream>>>(g, d_out, tbn_g, tbn_be, tsum, tsq, flagp); CK(11);

  if (errStage) {
    int ec = errCode > 999 ? 999 : errCode;
    sent_k<<<64, 256, 0, stream>>>((float*)d_out, (float)(errStage*1000 + ec));
  }
  #undef CK
}

// Round 10
// 782.201 us; speedup vs baseline: 1.0634x; 1.0634x over previous
//
#include <hip/hip_runtime.h>
#include <hip/hip_bf16.h>

typedef unsigned short u16;
typedef __attribute__((ext_vector_type(8))) __bf16 bf16x8;
typedef __attribute__((ext_vector_type(8))) u16 u16x8;
typedef __attribute__((ext_vector_type(4))) u16 u16x4;
typedef __attribute__((ext_vector_type(4))) float floatx4;

#define C_     512
#define NC_    12
#define BT_    1024
#define SEQ_   21
#define M_REG  21504
#define M_GAT  12288

__device__ __forceinline__ float bf2f(u16 u) {
  unsigned int v = ((unsigned int)u) << 16;
  float f; __builtin_memcpy(&f, &v, 4); return f;
}
__device__ __forceinline__ u16 f2bf(float f) {
  unsigned int b; __builtin_memcpy(&b, &f, 4);
  unsigned int r = (b + 0x7FFFu + ((b >> 16) & 1u)) >> 16;
  return (u16)r;
}
__device__ __forceinline__ float ldf(const void* p, size_t i, int f32) {
  return f32 ? ((const float*)p)[i] : bf2f(((const u16*)p)[i]);
}
__device__ __forceinline__ u16 ldbf(const void* p, size_t i, int f32) {
  return f32 ? f2bf(((const float*)p)[i]) : ((const u16*)p)[i];
}
__device__ __forceinline__ void stout(void* p, size_t i, float v, int f32) {
  if (f32) ((float*)p)[i] = v; else ((u16*)p)[i] = f2bf(v);
}

typedef __attribute__((address_space(1))) unsigned int as1_u32;
typedef __attribute__((address_space(3))) unsigned int as3_u32;
__device__ __forceinline__ void gl2lds16(const void* g, void* l) {
  __builtin_amdgcn_global_load_lds((const as1_u32*)g, (as3_u32*)l, 16, 0, 0);
}

__global__ void sent_k(float* __restrict__ o, float val) {
  const int i = blockIdx.x * 256 + threadIdx.x;
  if (i < 16384) o[i] = val;
}

// block 0: dtype detect; blocks 1..: zero the stats region
__global__ void detect_k(const u16* __restrict__ x, int* __restrict__ flag,
                         float* __restrict__ stats, int nstat) {
  if (blockIdx.x == 0) {
    __shared__ int cnt;
    if (threadIdx.x == 0) cnt = 0;
    __syncthreads();
    int bad = 0;
    for (int i = threadIdx.x; i < 4096; i += 256) {
      const float v = bf2f(x[i]);
      const float a = fabsf(v);
      if (!(a <= 1e4f)) bad++;
      else if (a > 0.f && a < 1e-35f) bad++;
    }
    atomicAdd(&cnt, bad);
    __syncthreads();
    if (threadIdx.x == 0) *flag = (cnt > 400) ? 1 : 0;
  } else {
    const int id = (blockIdx.x - 1) * 256 + threadIdx.x;
    if (id < nstat) stats[id] = 0.f;
  }
}

__global__ void transpose512(const void* __restrict__ rW, const void* __restrict__ cW,
                             const void* __restrict__ gW, u16* __restrict__ oR,
                             u16* __restrict__ oC, u16* __restrict__ oG,
                             const int* __restrict__ flagp) {
  const int f32 = *flagp;
  const int z = blockIdx.z;
  const void* src; u16* dst; size_t sofs = 0;
  if (z < 4)       { src = rW; sofs = (size_t)z*262144;     dst = oR + (size_t)z*262144; }
  else if (z < 16) { src = cW; sofs = (size_t)(z-4)*262144; dst = oC + (size_t)(z-4)*262144; }
  else             { src = gW;                              dst = oG; }
  __shared__ u16 t[32][33];
  const int tx = threadIdx.x;
  const int cy = blockIdx.y * 32, dx = blockIdx.x * 32;
  for (int i = threadIdx.y; i < 32; i += 8)
    t[i][tx] = ldbf(src, sofs + (size_t)(cy + i)*512 + dx + tx, f32);
  __syncthreads();
  for (int i = threadIdx.y; i < 32; i += 8)
    dst[(size_t)(dx + i)*512 + cy + tx] = t[tx][i];
}

// MODE 0: regions (A = x, maybe fp32; z = region). MODE 1: classes (zeff = n0+z).
// MODE 2: GAT projection (no bias/stats).  [R7-proven structure: BK=32]
template<int MODE>
__global__ __launch_bounds__(256)
void gemm_k(const void* __restrict__ Abase, const u16* __restrict__ Wtb,
            const void* __restrict__ biasb, u16* __restrict__ outb,
            float* __restrict__ ssumb, float* __restrict__ ssqb,
            const int* __restrict__ flagp, int pk, int n0)
{
  const int f32 = *flagp;
  const int z = blockIdx.z;
  const int zeff = (MODE == 1) ? (n0 + z) : z;
  const void* A = Abase;
  if (MODE == 1) A = (const void*)((const u16*)Abase +
        (size_t)((pk >> (zeff * 2)) & 3) * ((size_t)M_REG * C_));
  const u16* Wt = Wtb + (size_t)zeff * C_ * C_;
  u16* Out = outb + (size_t)z * (size_t)M_REG * C_;

  __shared__ __align__(16) u16 smem[64 * 132];   // 16896 B
  u16* As = smem;
  u16* Bs = smem + 4096;

  const int tid  = threadIdx.x;
  const int w    = tid >> 6;
  const int lane = tid & 63;
  const int wm   = w >> 1, wn = w & 1;
  const int r16  = lane & 15, q = lane >> 4;

  const int band = (MODE == 2) ? 12 : 21;
  const int lin  = blockIdx.x;
  const int xcd  = lin & 7;
  const int idx  = lin >> 3;
  const int mi   = xcd * band + idx % band;
  const int ni   = idx / band;
  const int m0   = mi * 128;
  const int nn0  = ni * 128;

  const int sub = lane >> 2;
  const int kq  = (lane & 3) * 8;
  const int am0 = m0 + w*32 + sub;
  const int am1 = am0 + 16;
  long ga0, ga1;
  if (MODE == 0) {
    const int roff = (pk >> (z * 8)) & 0xFF;
    int q21 = am0 / 21; int rm = am0 - q21*21;
    ga0 = (long)q21*49 + roff + rm;
    q21 = am1 / 21; rm = am1 - q21*21;
    ga1 = (long)q21*49 + roff + rm;
  } else { ga0 = am0; ga1 = am1; }
  const size_t aOff0 = (size_t)ga0 * C_ + kq;
  const size_t aOff1 = (size_t)ga1 * C_ + kq;
  const u16* bSrc0 = Wt + (size_t)(nn0 + w*32 + sub) * C_ + kq;
  const u16* bSrc1 = bSrc0 + (size_t)16 * C_;
  u16* aDstW0 = &As[(w*32 +  0) * 32];
  u16* aDstW1 = &As[(w*32 + 16) * 32];
  u16* bDstW0 = &Bs[(w*32 +  0) * 32];
  u16* bDstW1 = &Bs[(w*32 + 16) * 32];
  u16x8* aLds0 = (u16x8*)&As[(w*32 + sub +  0) * 32 + kq];
  u16x8* aLds1 = (u16x8*)&As[(w*32 + sub + 16) * 32 + kq];

  floatx4 acc[4][4];
  #pragma unroll
  for (int i = 0; i < 4; i++)
    #pragma unroll
    for (int j = 0; j < 4; j++)
      acc[i][j] = (floatx4){0.f, 0.f, 0.f, 0.f};

  for (int kk = 0; kk < C_; kk += 32) {
    if (MODE == 0 && f32) {
      const float* p0 = (const float*)A + aOff0 + kk;
      const float* p1 = (const float*)A + aOff1 + kk;
      const floatx4 f00 = *(const floatx4*)p0;
      const floatx4 f01 = *(const floatx4*)(p0 + 4);
      const floatx4 f10 = *(const floatx4*)p1;
      const floatx4 f11 = *(const floatx4*)(p1 + 4);
      u16x8 va0, va1;
      #pragma unroll
      for (int j = 0; j < 4; j++) {
        va0[j] = f2bf(f00[j]); va0[4+j] = f2bf(f01[j]);
        va1[j] = f2bf(f10[j]); va1[4+j] = f2bf(f11[j]);
      }
      __syncthreads();
      gl2lds16(bSrc0, bDstW0); gl2lds16(bSrc1, bDstW1);
      *aLds0 = va0; *aLds1 = va1;
      __syncthreads();
    } else {
      __syncthreads();
      gl2lds16((const u16*)A + aOff0 + kk, aDstW0);
      gl2lds16((const u16*)A + aOff1 + kk, aDstW1);
      gl2lds16(bSrc0, bDstW0);
      gl2lds16(bSrc1, bDstW1);
      __syncthreads();
    }
    bSrc0 += 32; bSrc1 += 32;
    bf16x8 av[4], bv[4];
    #pragma unroll
    for (int mt = 0; mt < 4; mt++)
      av[mt] = *(const bf16x8*)&As[(wm*64 + mt*16 + r16)*32 + q*8];
    #pragma unroll
    for (int nt = 0; nt < 4; nt++)
      bv[nt] = *(const bf16x8*)&Bs[(wn*64 + nt*16 + r16)*32 + q*8];
    #pragma unroll
    for (int mt = 0; mt < 4; mt++)
      #pragma unroll
      for (int nt = 0; nt < 4; nt++)
        acc[mt][nt] = __builtin_amdgcn_mfma_f32_16x16x32_bf16(av[mt], bv[nt], acc[mt][nt], 0, 0, 0);
  }

  // ---- epilogue: bias+stats in regs, LDS transpose, coalesced 16B stores ----
  #pragma unroll
  for (int rh = 0; rh < 2; rh++) {
    __syncthreads();
    if (wm == rh) {
      #pragma unroll
      for (int nt = 0; nt < 4; nt++) {
        const int lcol = wn*64 + nt*16 + r16;
        float bvv = 0.f;
        if (MODE != 2) bvv = ldf(biasb, (size_t)zeff * C_ + nn0 + lcol, f32);
        float s = 0.f, s2 = 0.f;
        #pragma unroll
        for (int mt = 0; mt < 4; mt++) {
          #pragma unroll
          for (int p = 0; p < 4; p++) {
            const float v = acc[mt][nt][p] + bvv;
            s += v; s2 += v*v;
            smem[(mt*16 + q*4 + p)*132 + lcol] = f2bf(v);
          }
        }
        if (MODE != 2) {
          s  += __shfl_xor(s, 16);  s  += __shfl_xor(s, 32);
          s2 += __shfl_xor(s2, 16); s2 += __shfl_xor(s2, 32);
          if (q == 0) {
            atomicAdd(&ssumb[(size_t)zeff * C_ + nn0 + lcol], s);
            atomicAdd(&ssqb [(size_t)zeff * C_ + nn0 + lcol], s2);
          }
        }
      }
    }
    __syncthreads();
    #pragma unroll
    for (int rr = 0; rr < 4; rr++) {
      const int rl = rr*16 + (tid >> 4);
      const int cc = (tid & 15) * 8;
      const u16x8 vv = *(const u16x8*)&smem[rl*132 + cc];
      u16x8* dst = (u16x8*)&Out[(size_t)(m0 + rh*64 + rl) * C_ + nn0 + cc];
      if (MODE == 1) __builtin_nontemporal_store(vv, dst);
      else           *dst = vv;
    }
  }
}

// ---- region BN+relu (in-place) + seq-mean -> hbar; 8 channels/lane ----
__global__ void bn_region(u16* __restrict__ h, float* __restrict__ hbar,
                          const void* __restrict__ gamma, const void* __restrict__ beta,
                          const float* __restrict__ rsum, const float* __restrict__ rsq,
                          const int* __restrict__ flagp) {
  const int f32 = *flagp;
  const int gid  = blockIdx.x;
  const int r    = gid >> 8;
  const int bt   = ((gid & 255) << 2) + (threadIdx.x >> 6);
  const int lane = threadIdx.x & 63;
  const int d0   = lane * 8;
  const int rd   = r*512 + d0;
  float sc[8], sh[8], accv[8];
  #pragma unroll
  for (int j = 0; j < 8; j++) {
    const float mean = rsum[rd+j] * (1.f/21504.f);
    const float var  = fmaxf(rsq[rd+j] * (1.f/21504.f) - mean*mean, 0.f);
    sc[j] = ldf(gamma, rd+j, f32) * rsqrtf(var + 1e-5f);
    sh[j] = ldf(beta,  rd+j, f32) - mean * sc[j];
    accv[j] = 0.f;
  }
  const size_t base = ((size_t)r * M_REG + (size_t)bt * SEQ_) * C_ + d0;
  #pragma unroll
  for (int s = 0; s < SEQ_; s++) {
    u16x8 vv = *(u16x8*)&h[base + (size_t)s*C_];
    #pragma unroll
    for (int j = 0; j < 8; j++) {
      float v = fmaxf(sc[j] * bf2f(vv[j]) + sh[j], 0.f);
      vv[j] = f2bf(v);
      accv[j] += v;
    }
    *(u16x8*)&h[base + (size_t)s*C_] = vv;
  }
  float* hb = &hbar[((size_t)r * BT_ + bt) * C_ + d0];
  #pragma unroll
  for (int j = 0; j < 8; j++) hb[j] = accv[j] * (1.f/21.f);
}

// ---- prediction heads: wave-parallel dot products ----
__global__ void preds_k(const float* __restrict__ hbar,
                        const void* __restrict__ upW,  const void* __restrict__ upB,
                        const void* __restrict__ midW, const void* __restrict__ midB,
                        const void* __restrict__ d1W,  const void* __restrict__ d1B,
                        const void* __restrict__ d2W,  const void* __restrict__ d2B,
                        void* __restrict__ dout, const int* __restrict__ flagp) {
  const int f32 = *flagp;
  const int bt = blockIdx.x;
  __shared__ float hl[4][512];
  for (int i = threadIdx.x; i < 2048; i += 256)
    hl[i >> 9][i & 511] = hbar[((size_t)(i >> 9) * BT_ + bt) * C_ + (i & 511)];
  __syncthreads();
  const int w = threadIdx.x >> 6, lane = threadIdx.x & 63;
  for (int j = w; j < 42; j += 4) {
    int r, wdt, col; const void *W, *Bv; size_t oofs;
    if (j < 16)      { r=0; W=upW;  Bv=upB;  wdt=16; col=j;    oofs = (size_t)bt*16 + col; }
    else if (j < 18) { r=1; W=midW; Bv=midB; wdt=2;  col=j-16; oofs = 16384 + (size_t)bt*2 + col; }
    else if (j < 26) { r=2; W=d1W;  Bv=d1B;  wdt=8;  col=j-18; oofs = 18432 + (size_t)bt*8 + col; }
    else             { r=3; W=d2W;  Bv=d2B;  wdt=16; col=j-26; oofs = 26624 + (size_t)bt*16 + col; }
    float acc = 0.f;
    #pragma unroll
    for (int e = 0; e < 8; e++) {
      const int d = lane*8 + e;
      acc += hl[r][d] * ldf(W, (size_t)d*wdt + col, f32);
    }
    #pragma unroll
    for (int off = 32; off; off >>= 1) acc += __shfl_xor(acc, off);
    if (lane == 0) stout(dout, oofs, acc + ldf(Bv, col, f32), f32);
  }
}

// ---- class BN+relu + seq-mean -> f_v; 8 channels/lane ----
__global__ void bn_class_mean(const u16* __restrict__ ypre, u16* __restrict__ fv,
                              const void* __restrict__ gamma, const void* __restrict__ beta,
                              const float* __restrict__ csum, const float* __restrict__ csq,
                              const int* __restrict__ flagp, int n0) {
  const int f32 = *flagp;
  const int gid  = blockIdx.x;
  const int zz   = gid >> 8;
  const int bt   = ((gid & 255) << 2) + (threadIdx.x >> 6);
  const int lane = threadIdx.x & 63;
  const int d0   = lane * 8;
  const int n    = n0 + zz;
  const int nd   = n*512 + d0;
  float sc[8], sh[8], accv[8];
  #pragma unroll
  for (int j = 0; j < 8; j++) {
    const float mean = csum[nd+j] * (1.f/21504.f);
    const float var  = fmaxf(csq[nd+j] * (1.f/21504.f) - mean*mean, 0.f);
    sc[j] = ldf(gamma, nd+j, f32) * rsqrtf(var + 1e-5f);
    sh[j] = ldf(beta,  nd+j, f32) - mean * sc[j];
    accv[j] = 0.f;
  }
  const size_t base = ((size_t)zz * M_REG + (size_t)bt * SEQ_) * C_ + d0;
  #pragma unroll
  for (int s = 0; s < SEQ_; s++) {
    const u16x8 vv = *(const u16x8*)&ypre[base + (size_t)s*C_];
    #pragma unroll
    for (int j = 0; j < 8; j++)
      accv[j] += fmaxf(sc[j] * bf2f(vv[j]) + sh[j], 0.f);
  }
  u16x8 ov;
  #pragma unroll
  for (int j = 0; j < 8; j++) ov[j] = f2bf(accv[j] * (1.f/21.f));
  *(u16x8*)&fv[((size_t)bt * NC_ + n) * C_ + d0] = ov;
}

__global__ __launch_bounds__(256)
void gat_k(const u16* __restrict__ hg, const u16* __restrict__ fv,
           const void* __restrict__ al, const void* __restrict__ ar,
           const void* __restrict__ adj_mask, float* __restrict__ g,
           const int* __restrict__ flagp) {
  const int f32 = *flagp;
  const int bt = blockIdx.x;
  __shared__ float hl[12][512];
  __shared__ float alv[12], arv[12], attn[12][12];
  const u16* hgb = hg + (size_t)bt * NC_ * C_;
  for (int i = threadIdx.x * 8; i < 6144; i += 2048) {
    const u16x8 vv = *(const u16x8*)&hgb[i];
    const int ii = i >> 9, cc = i & 511;
    #pragma unroll
    for (int e = 0; e < 8; e++) hl[ii][cc + e] = bf2f(vv[e]);
  }
  __syncthreads();
  const int w = threadIdx.x >> 6, lane = threadIdx.x & 63;
  for (int i = w; i < 12; i += 4) {
    float pa = 0.f, pr = 0.f;
    #pragma unroll
    for (int jj = 0; jj < 8; jj++) {
      const int c = lane*8 + jj;
      const float hv = hl[i][c];
      pa += hv * ldf(al, c, f32);
      pr += hv * ldf(ar, c, f32);
    }
    #pragma unroll
    for (int off = 32; off; off >>= 1) { pa += __shfl_xor(pa, off); pr += __shfl_xor(pr, off); }
    if (lane == 0) { alv[i] = pa; arv[i] = pr; }
  }
  __syncthreads();
  if (threadIdx.x < 12) {
    const unsigned AM[12] = {0xFE8,0xFE8,0xFE8,0xFF7,0xFE8,0x1DF,
                             0xE3F,0xE3F,0xE3F,0x1DF,0x1DF,0x1DF};
    const int i = threadIdx.x;
    float row[12]; float mx = -1e30f;
    #pragma unroll
    for (int jx = 0; jx < 12; jx++) {
      const float maskv = ldf(adj_mask, (size_t)bt*144 + i*12 + jx, f32);
      const float adjv = (float)((AM[i] >> jx) & 1u) * maskv + (i == jx ? 1.f : 0.f);
      float e;
      if (adjv > 0.1f) {
        const float t = alv[i] + arv[jx];
        e = t > 0.f ? t : 0.2f * t;
      } else e = -1e9f;
      row[jx] = e; mx = fmaxf(mx, e);
    }
    float den = 0.f;
    #pragma unroll
    for (int jx = 0; jx < 12; jx++) { const float ex = __expf(row[jx] - mx); row[jx] = ex; den += ex; }
    const float inv = 1.f / den;
    #pragma unroll
    for (int jx = 0; jx < 12; jx++) attn[i][jx] = row[jx] * inv;
  }
  __syncthreads();
  const u16* fvb = fv + (size_t)bt * NC_ * C_;
  float* gb = g + (size_t)bt * NC_ * C_;
  for (int o = threadIdx.x; o < 6144; o += 256) {
    const int i = o >> 9, c = o & 511;
    float acc = bf2f(fvb[o]);
    #pragma unroll
    for (int jx = 0; jx < 12; jx++) acc += attn[i][jx] * hl[jx][c];
    gb[o] = acc;
  }
}

__global__ void tconv_k(float* __restrict__ g, const void* __restrict__ tw,
                        const void* __restrict__ tb, float* __restrict__ tsum,
                        float* __restrict__ tsq, const int* __restrict__ flagp) {
  const int f32 = *flagp;
  const int id = blockIdx.x * 256 + threadIdx.x;
  const int c = id & 511;
  const int n = (id >> 9) % 12;
  const int b = id / 6144;
  float wk[5];
  #pragma unroll
  for (int k = 0; k < 5; k++) wk[k] = ldf(tw, (size_t)(n*512 + c)*5 + k, f32);
  const float bias = ldf(tb, n*512 + c, f32);
  float xv[36];
  xv[0] = xv[1] = xv[34] = xv[35] = 0.f;
  const size_t base = ((size_t)b * 32 * NC_ + n) * C_ + c;
  #pragma unroll
  for (int t = 0; t < 32; t++) xv[t + 2] = g[base + (size_t)t * 6144];
  float s = 0.f, s2 = 0.f;
  float ov[32];
  #pragma unroll
  for (int t = 0; t < 32; t++) {
    float v = bias;
    #pragma unroll
    for (int k = 0; k < 5; k++) v += wk[k] * xv[t + k];
    ov[t] = v; s += v; s2 += v*v;
  }
  #pragma unroll
  for (int t = 0; t < 32; t++) g[base + (size_t)t * 6144] = ov[t];
  #pragma unroll
  for (int off = 32; off; off >>= 1) { s += __shfl_xor(s, off); s2 += __shfl_xor(s2, off); }
  if ((threadIdx.x & 63) == 0) { atomicAdd(&tsum[n], s); atomicAdd(&tsq[n], s2); }
}

// ---- final BN+relu -> d_out; 4 elems/thread ----
__global__ void bn_t(const float* __restrict__ v, void* __restrict__ outp,
                     const void* __restrict__ tg, const void* __restrict__ tb2,
                     const float* __restrict__ tsum, const float* __restrict__ tsq,
                     const int* __restrict__ flagp) {
  const int f32 = *flagp;
  const size_t id4 = (size_t)blockIdx.x * 256 + threadIdx.x;
  const int n = (int)((id4 >> 7) % 12);
  const float mean = tsum[n] * (1.f/524288.f);
  const float var  = fmaxf(tsq[n] * (1.f/524288.f) - mean*mean, 0.f);
  const float sc = ldf(tg, n, f32) * rsqrtf(var + 1e-5f);
  const float sh = ldf(tb2, n, f32) - mean * sc;
  const floatx4 vv = *(const floatx4*)&v[id4 * 4];
  if (f32) {
    floatx4 ov;
    #pragma unroll
    for (int e = 0; e < 4; e++) ov[e] = fmaxf(sc * vv[e] + sh, 0.f);
    *(floatx4*)&((float*)outp)[43008 + id4*4] = ov;
  } else {
    u16x4 ov;
    #pragma unroll
    for (int e = 0; e < 4; e++) ov[e] = f2bf(fmaxf(sc * vv[e] + sh, 0.f));
    *(u16x4*)&((u16*)outp)[43008 + id4*4] = ov;
  }
}

static constexpr size_t OFF_FLAG = 0;
static constexpr size_t OFF_STAT = 64;
static constexpr int    STAT_N   = 2048+2048+6144+6144+12+12;
static constexpr size_t OFF_WTR  = 65792;
static constexpr size_t OFF_WTC  = OFF_WTR + (size_t)4*512*512*2;
static constexpr size_t OFF_WTG  = OFF_WTC + (size_t)12*512*512*2;
static constexpr size_t OFF_H    = OFF_WTG + (size_t)512*512*2;
static constexpr size_t OFF_HBAR = OFF_H + (size_t)4*M_REG*C_*2;
static constexpr size_t OFF_FV   = OFF_HBAR + (size_t)4*BT_*C_*4;
static constexpr size_t OFF_AREN = OFF_FV + (size_t)M_GAT*C_*2;
static constexpr size_t YPRE_B   = (size_t)M_REG * C_ * 2;
static constexpr size_t NEEDED   = OFF_AREN + YPRE_B;

extern "C" void kernel_launch(void* const* d_in, const int* in_sizes, int n_in,
                              void* d_out, int out_size, void* d_ws, size_t ws_size,
                              hipStream_t stream) {
  const u16* x        = (const u16*)d_in[0];
  const void* adj_m   = d_in[1];
  const void* region_W= d_in[2];
  const void* region_b= d_in[3];
  const void* region_g= d_in[4];
  const void* region_be=d_in[5];
  const void* upW  = d_in[6];   const void* upB  = d_in[7];
  const void* midW = d_in[8];   const void* midB = d_in[9];
  const void* d1W  = d_in[10];  const void* d1B  = d_in[11];
  const void* d2W  = d_in[12];  const void* d2B  = d_in[13];
  const void* class_W = d_in[14];
  const void* class_b = d_in[15];
  const void* class_g = d_in[16];
  const void* class_be= d_in[17];
  const void* gat_W   = d_in[18];
  const void* gat_al  = d_in[19];
  const void* gat_ar  = d_in[20];
  const void* tconv_W = d_in[21];
  const void* tconv_b = d_in[22];
  const void* tbn_g   = d_in[23];
  const void* tbn_be  = d_in[24];

  char* ws = (char*)d_ws;
  int*   flagp = (int*)(ws + OFF_FLAG);
  float* rsum = (float*)(ws + OFF_STAT);
  float* rsq  = rsum + 2048;
  float* csum = rsq  + 2048;
  float* csq  = csum + 6144;
  float* tsum = csq  + 6144;
  float* tsq  = tsum + 12;
  u16*   WtR  = (u16*)(ws + OFF_WTR);
  u16*   WtC  = (u16*)(ws + OFF_WTC);
  u16*   WtG  = (u16*)(ws + OFF_WTG);
  u16*   h    = (u16*)(ws + OFF_H);
  float* hbar = (float*)(ws + OFF_HBAR);
  u16*   fv   = (u16*)(ws + OFF_FV);
  u16*   ypre = (u16*)(ws + OFF_AREN);
  u16*   hg   = (u16*)(ws + OFF_AREN);
  float* g    = (float*)(ws + OFF_H);

  int errStage = 0, errCode = 0;
  (void)hipGetLastError();
  #define CK(s) do { hipError_t e_ = hipGetLastError(); \
      if (e_ != hipSuccess && errStage == 0) { errStage = (s); errCode = (int)e_; } } while(0)

  if (ws_size < NEEDED) {
    int mb = (int)(ws_size >> 20); if (mb > 999) mb = 999;
    sent_k<<<64, 256, 0, stream>>>((float*)d_out, 13000.f + (float)mb);
    return;
  }

  int nch = (int)((ws_size - OFF_AREN) / YPRE_B);
  if (nch > 12) nch = 12;
  if (nch < 1) nch = 1;

  const int ROFFPACK = 0 | (14 << 8) | (28 << 16) | (28 << 24);
  const int SELPACK  = (1 << 6) | (3 << 10) | (2 << 12) | (2 << 14) |
                       (2 << 16) | (3 << 18) | (3 << 20) | (3 << 22);

  detect_k<<<1 + (STAT_N + 255)/256, 256, 0, stream>>>(x, flagp, rsum, STAT_N); CK(1);
  transpose512<<<dim3(16,16,17), dim3(32,8), 0, stream>>>(
      region_W, class_W, gat_W, WtR, WtC, WtG, flagp);               CK(2);

  gemm_k<0><<<dim3(672,1,4), 256, 0, stream>>>(
      x, WtR, region_b, h, rsum, rsq, flagp, ROFFPACK, 0);           CK(3);
  bn_region<<<1024, 256, 0, stream>>>(h, hbar, region_g, region_be,
      rsum, rsq, flagp);                                             CK(4);
  preds_k<<<1024, 256, 0, stream>>>(hbar, upW,upB, midW,midB,
      d1W,d1B, d2W,d2B, d_out, flagp);                               CK(5);

  for (int n0 = 0; n0 < 12; n0 += nch) {
    const int zc = (12 - n0) < nch ? (12 - n0) : nch;
    gemm_k<1><<<dim3(672,1,zc), 256, 0, stream>>>(
        h, WtC, class_b, ypre, csum, csq, flagp, SELPACK, n0);       CK(6);
    bn_class_mean<<<zc*256, 256, 0, stream>>>(ypre, fv, class_g, class_be,
        csum, csq, flagp, n0);                                       CK(7);
  }

  gemm_k<2><<<dim3(384,1,1), 256, 0, stream>>>(
      fv, WtG, nullptr, hg, nullptr, nullptr, flagp, 0, 0);          CK(8);
  gat_k<<<1024, 256, 0, stream>>>(hg, fv, gat_al, gat_ar, adj_m, g, flagp); CK(9);
  tconv_k<<<768, 256, 0, stream>>>(g, tconv_W, tconv_b, tsum, tsq, flagp);  CK(10);
  bn_t<<<6144, 256, 0, stream>>>(g, d_out, tbn_g, tbn_be, tsum, tsq, flagp); CK(11);

  if (errStage) {
    int ec = errCode > 999 ? 999 : errCode;
    sent_k<<<64, 256, 0, stream>>>((float*)d_out, (float)(errStage*1000 + ec));
  }
  #undef CK
}

// Round 11
// 753.912 us; speedup vs baseline: 1.1033x; 1.0375x over previous
//
#include <hip/hip_runtime.h>
#include <hip/hip_bf16.h>

typedef unsigned short u16;
typedef __attribute__((ext_vector_type(8))) __bf16 bf16x8;
typedef __attribute__((ext_vector_type(8))) u16 u16x8;
typedef __attribute__((ext_vector_type(4))) u16 u16x4;
typedef __attribute__((ext_vector_type(4))) float floatx4;

#define C_     512
#define NC_    12
#define BT_    1024
#define SEQ_   21
#define M_REG  21504
#define M_GAT  12288

__device__ __forceinline__ float bf2f(u16 u) {
  unsigned int v = ((unsigned int)u) << 16;
  float f; __builtin_memcpy(&f, &v, 4); return f;
}
__device__ __forceinline__ u16 f2bf(float f) {
  unsigned int b; __builtin_memcpy(&b, &f, 4);
  unsigned int r = (b + 0x7FFFu + ((b >> 16) & 1u)) >> 16;
  return (u16)r;
}
__device__ __forceinline__ float ldf(const void* p, size_t i, int f32) {
  return f32 ? ((const float*)p)[i] : bf2f(((const u16*)p)[i]);
}
__device__ __forceinline__ u16 ldbf(const void* p, size_t i, int f32) {
  return f32 ? f2bf(((const float*)p)[i]) : ((const u16*)p)[i];
}
__device__ __forceinline__ void stout(void* p, size_t i, float v, int f32) {
  if (f32) ((float*)p)[i] = v; else ((u16*)p)[i] = f2bf(v);
}

typedef __attribute__((address_space(1))) unsigned int as1_u32;
typedef __attribute__((address_space(3))) unsigned int as3_u32;
__device__ __forceinline__ void gl2lds16(const void* g, void* l) {
  __builtin_amdgcn_global_load_lds((const as1_u32*)g, (as3_u32*)l, 16, 0, 0);
}

__global__ void sent_k(float* __restrict__ o, float val) {
  const int i = blockIdx.x * 256 + threadIdx.x;
  if (i < 16384) o[i] = val;
}

// block 0: dtype detect; blocks 1..: zero the stats region
__global__ void detect_k(const u16* __restrict__ x, int* __restrict__ flag,
                         float* __restrict__ stats, int nstat) {
  if (blockIdx.x == 0) {
    __shared__ int cnt;
    if (threadIdx.x == 0) cnt = 0;
    __syncthreads();
    int bad = 0;
    for (int i = threadIdx.x; i < 4096; i += 256) {
      const float v = bf2f(x[i]);
      const float a = fabsf(v);
      if (!(a <= 1e4f)) bad++;
      else if (a > 0.f && a < 1e-35f) bad++;
    }
    atomicAdd(&cnt, bad);
    __syncthreads();
    if (threadIdx.x == 0) *flag = (cnt > 400) ? 1 : 0;
  } else {
    const int id = (blockIdx.x - 1) * 256 + threadIdx.x;
    if (id < nstat) stats[id] = 0.f;
  }
}

__global__ void transpose512(const void* __restrict__ rW, const void* __restrict__ cW,
                             const void* __restrict__ gW, u16* __restrict__ oR,
                             u16* __restrict__ oC, u16* __restrict__ oG,
                             const int* __restrict__ flagp) {
  const int f32 = *flagp;
  const int z = blockIdx.z;
  const void* src; u16* dst; size_t sofs = 0;
  if (z < 4)       { src = rW; sofs = (size_t)z*262144;     dst = oR + (size_t)z*262144; }
  else if (z < 16) { src = cW; sofs = (size_t)(z-4)*262144; dst = oC + (size_t)(z-4)*262144; }
  else             { src = gW;                              dst = oG; }
  __shared__ u16 t[32][33];
  const int tx = threadIdx.x;
  const int cy = blockIdx.y * 32, dx = blockIdx.x * 32;
  for (int i = threadIdx.y; i < 32; i += 8)
    t[i][tx] = ldbf(src, sofs + (size_t)(cy + i)*512 + dx + tx, f32);
  __syncthreads();
  for (int i = threadIdx.y; i < 32; i += 8)
    dst[(size_t)(dx + i)*512 + cy + tx] = t[tx][i];
}

// MODE 0: regions (A = x, maybe fp32; z = region). MODE 1: classes (zeff = n0+z).
// MODE 2: GAT projection (no bias/stats).  [R7 K-loop; single-pass epilogue]
template<int MODE>
__global__ __launch_bounds__(256)
void gemm_k(const void* __restrict__ Abase, const u16* __restrict__ Wtb,
            const void* __restrict__ biasb, u16* __restrict__ outb,
            float* __restrict__ ssumb, float* __restrict__ ssqb,
            const int* __restrict__ flagp, int pk, int n0)
{
  const int f32 = *flagp;
  const int z = blockIdx.z;
  const int zeff = (MODE == 1) ? (n0 + z) : z;
  const void* A = Abase;
  if (MODE == 1) A = (const void*)((const u16*)Abase +
        (size_t)((pk >> (zeff * 2)) & 3) * ((size_t)M_REG * C_));
  const u16* Wt = Wtb + (size_t)zeff * C_ * C_;
  u16* Out = outb + (size_t)z * (size_t)M_REG * C_;

  __shared__ __align__(16) u16 smem[128 * 132];   // 33792 B; K-loop uses first 16 KB
  u16* As = smem;
  u16* Bs = smem + 4096;

  const int tid  = threadIdx.x;
  const int w    = tid >> 6;
  const int lane = tid & 63;
  const int wm   = w >> 1, wn = w & 1;
  const int r16  = lane & 15, q = lane >> 4;

  const int band = (MODE == 2) ? 12 : 21;
  const int lin  = blockIdx.x;
  const int xcd  = lin & 7;
  const int idx  = lin >> 3;
  const int mi   = xcd * band + idx % band;
  const int ni   = idx / band;
  const int m0   = mi * 128;
  const int nn0  = ni * 128;

  const int sub = lane >> 2;
  const int kq  = (lane & 3) * 8;
  const int am0 = m0 + w*32 + sub;
  const int am1 = am0 + 16;
  long ga0, ga1;
  if (MODE == 0) {
    const int roff = (pk >> (z * 8)) & 0xFF;
    int q21 = am0 / 21; int rm = am0 - q21*21;
    ga0 = (long)q21*49 + roff + rm;
    q21 = am1 / 21; rm = am1 - q21*21;
    ga1 = (long)q21*49 + roff + rm;
  } else { ga0 = am0; ga1 = am1; }
  const size_t aOff0 = (size_t)ga0 * C_ + kq;
  const size_t aOff1 = (size_t)ga1 * C_ + kq;
  const u16* bSrc0 = Wt + (size_t)(nn0 + w*32 + sub) * C_ + kq;
  const u16* bSrc1 = bSrc0 + (size_t)16 * C_;
  u16* aDstW0 = &As[(w*32 +  0) * 32];
  u16* aDstW1 = &As[(w*32 + 16) * 32];
  u16* bDstW0 = &Bs[(w*32 +  0) * 32];
  u16* bDstW1 = &Bs[(w*32 + 16) * 32];
  u16x8* aLds0 = (u16x8*)&As[(w*32 + sub +  0) * 32 + kq];
  u16x8* aLds1 = (u16x8*)&As[(w*32 + sub + 16) * 32 + kq];

  floatx4 acc[4][4];
  #pragma unroll
  for (int i = 0; i < 4; i++)
    #pragma unroll
    for (int j = 0; j < 4; j++)
      acc[i][j] = (floatx4){0.f, 0.f, 0.f, 0.f};

  for (int kk = 0; kk < C_; kk += 32) {
    if (MODE == 0 && f32) {
      const float* p0 = (const float*)A + aOff0 + kk;
      const float* p1 = (const float*)A + aOff1 + kk;
      const floatx4 f00 = *(const floatx4*)p0;
      const floatx4 f01 = *(const floatx4*)(p0 + 4);
      const floatx4 f10 = *(const floatx4*)p1;
      const floatx4 f11 = *(const floatx4*)(p1 + 4);
      u16x8 va0, va1;
      #pragma unroll
      for (int j = 0; j < 4; j++) {
        va0[j] = f2bf(f00[j]); va0[4+j] = f2bf(f01[j]);
        va1[j] = f2bf(f10[j]); va1[4+j] = f2bf(f11[j]);
      }
      __syncthreads();
      gl2lds16(bSrc0, bDstW0); gl2lds16(bSrc1, bDstW1);
      *aLds0 = va0; *aLds1 = va1;
      __syncthreads();
    } else {
      __syncthreads();
      gl2lds16((const u16*)A + aOff0 + kk, aDstW0);
      gl2lds16((const u16*)A + aOff1 + kk, aDstW1);
      gl2lds16(bSrc0, bDstW0);
      gl2lds16(bSrc1, bDstW1);
      __syncthreads();
    }
    bSrc0 += 32; bSrc1 += 32;
    bf16x8 av[4], bv[4];
    #pragma unroll
    for (int mt = 0; mt < 4; mt++)
      av[mt] = *(const bf16x8*)&As[(wm*64 + mt*16 + r16)*32 + q*8];
    #pragma unroll
    for (int nt = 0; nt < 4; nt++)
      bv[nt] = *(const bf16x8*)&Bs[(wn*64 + nt*16 + r16)*32 + q*8];
    #pragma unroll
    for (int mt = 0; mt < 4; mt++)
      #pragma unroll
      for (int nt = 0; nt < 4; nt++)
        acc[mt][nt] = __builtin_amdgcn_mfma_f32_16x16x32_bf16(av[mt], bv[nt], acc[mt][nt], 0, 0, 0);
  }

  // ---- single-pass epilogue: bias+stats in regs, full 128x132 LDS, 16B stores ----
  __syncthreads();
  #pragma unroll
  for (int nt = 0; nt < 4; nt++) {
    const int lcol = wn*64 + nt*16 + r16;
    float bvv = 0.f;
    if (MODE != 2) bvv = ldf(biasb, (size_t)zeff * C_ + nn0 + lcol, f32);
    float s = 0.f, s2 = 0.f;
    #pragma unroll
    for (int mt = 0; mt < 4; mt++) {
      #pragma unroll
      for (int p = 0; p < 4; p++) {
        const float v = acc[mt][nt][p] + bvv;
        s += v; s2 += v*v;
        smem[(wm*64 + mt*16 + q*4 + p)*132 + lcol] = f2bf(v);
      }
    }
    if (MODE != 2) {
      s  += __shfl_xor(s, 16);  s  += __shfl_xor(s, 32);
      s2 += __shfl_xor(s2, 16); s2 += __shfl_xor(s2, 32);
      if (q == 0) {
        atomicAdd(&ssumb[(size_t)zeff * C_ + nn0 + lcol], s);
        atomicAdd(&ssqb [(size_t)zeff * C_ + nn0 + lcol], s2);
      }
    }
  }
  __syncthreads();
  #pragma unroll
  for (int rr = 0; rr < 8; rr++) {
    const int rl = rr*16 + (tid >> 4);
    const int cc = (tid & 15) * 8;
    const u16x8 vv = *(const u16x8*)&smem[rl*132 + cc];
    u16x8* dst = (u16x8*)&Out[(size_t)(m0 + rl) * C_ + nn0 + cc];
    if (MODE == 1) __builtin_nontemporal_store(vv, dst);
    else           *dst = vv;
  }
}

// ---- region BN+relu (in-place) + seq-mean -> hbar; 8 channels/lane ----
__global__ void bn_region(u16* __restrict__ h, float* __restrict__ hbar,
                          const void* __restrict__ gamma, const void* __restrict__ beta,
                          const float* __restrict__ rsum, const float* __restrict__ rsq,
                          const int* __restrict__ flagp) {
  const int f32 = *flagp;
  const int gid  = blockIdx.x;
  const int r    = gid >> 8;
  const int bt   = ((gid & 255) << 2) + (threadIdx.x >> 6);
  const int lane = threadIdx.x & 63;
  const int d0   = lane * 8;
  const int rd   = r*512 + d0;
  float sc[8], sh[8], accv[8];
  #pragma unroll
  for (int j = 0; j < 8; j++) {
    const float mean = rsum[rd+j] * (1.f/21504.f);
    const float var  = fmaxf(rsq[rd+j] * (1.f/21504.f) - mean*mean, 0.f);
    sc[j] = ldf(gamma, rd+j, f32) * rsqrtf(var + 1e-5f);
    sh[j] = ldf(beta,  rd+j, f32) - mean * sc[j];
    accv[j] = 0.f;
  }
  const size_t base = ((size_t)r * M_REG + (size_t)bt * SEQ_) * C_ + d0;
  #pragma unroll
  for (int s = 0; s < SEQ_; s++) {
    u16x8 vv = *(u16x8*)&h[base + (size_t)s*C_];
    #pragma unroll
    for (int j = 0; j < 8; j++) {
      float v = fmaxf(sc[j] * bf2f(vv[j]) + sh[j], 0.f);
      vv[j] = f2bf(v);
      accv[j] += v;
    }
    *(u16x8*)&h[base + (size_t)s*C_] = vv;
  }
  float* hb = &hbar[((size_t)r * BT_ + bt) * C_ + d0];
  #pragma unroll
  for (int j = 0; j < 8; j++) hb[j] = accv[j] * (1.f/21.f);
}

// ---- prediction heads: wave-parallel dot products ----
__global__ void preds_k(const float* __restrict__ hbar,
                        const void* __restrict__ upW,  const void* __restrict__ upB,
                        const void* __restrict__ midW, const void* __restrict__ midB,
                        const void* __restrict__ d1W,  const void* __restrict__ d1B,
                        const void* __restrict__ d2W,  const void* __restrict__ d2B,
                        void* __restrict__ dout, const int* __restrict__ flagp) {
  const int f32 = *flagp;
  const int bt = blockIdx.x;
  __shared__ float hl[4][512];
  for (int i = threadIdx.x; i < 2048; i += 256)
    hl[i >> 9][i & 511] = hbar[((size_t)(i >> 9) * BT_ + bt) * C_ + (i & 511)];
  __syncthreads();
  const int w = threadIdx.x >> 6, lane = threadIdx.x & 63;
  for (int j = w; j < 42; j += 4) {
    int r, wdt, col; const void *W, *Bv; size_t oofs;
    if (j < 16)      { r=0; W=upW;  Bv=upB;  wdt=16; col=j;    oofs = (size_t)bt*16 + col; }
    else if (j < 18) { r=1; W=midW; Bv=midB; wdt=2;  col=j-16; oofs = 16384 + (size_t)bt*2 + col; }
    else if (j < 26) { r=2; W=d1W;  Bv=d1B;  wdt=8;  col=j-18; oofs = 18432 + (size_t)bt*8 + col; }
    else             { r=3; W=d2W;  Bv=d2B;  wdt=16; col=j-26; oofs = 26624 + (size_t)bt*16 + col; }
    float acc = 0.f;
    #pragma unroll
    for (int e = 0; e < 8; e++) {
      const int d = lane*8 + e;
      acc += hl[r][d] * ldf(W, (size_t)d*wdt + col, f32);
    }
    #pragma unroll
    for (int off = 32; off; off >>= 1) acc += __shfl_xor(acc, off);
    if (lane == 0) stout(dout, oofs, acc + ldf(Bv, col, f32), f32);
  }
}

// ---- class BN+relu + seq-mean -> f_v; 8 channels/lane ----
__global__ void bn_class_mean(const u16* __restrict__ ypre, u16* __restrict__ fv,
                              const void* __restrict__ gamma, const void* __restrict__ beta,
                              const float* __restrict__ csum, const float* __restrict__ csq,
                              const int* __restrict__ flagp, int n0) {
  const int f32 = *flagp;
  const int gid  = blockIdx.x;
  const int zz   = gid >> 8;
  const int bt   = ((gid & 255) << 2) + (threadIdx.x >> 6);
  const int lane = threadIdx.x & 63;
  const int d0   = lane * 8;
  const int n    = n0 + zz;
  const int nd   = n*512 + d0;
  float sc[8], sh[8], accv[8];
  #pragma unroll
  for (int j = 0; j < 8; j++) {
    const float mean = csum[nd+j] * (1.f/21504.f);
    const float var  = fmaxf(csq[nd+j] * (1.f/21504.f) - mean*mean, 0.f);
    sc[j] = ldf(gamma, nd+j, f32) * rsqrtf(var + 1e-5f);
    sh[j] = ldf(beta,  nd+j, f32) - mean * sc[j];
    accv[j] = 0.f;
  }
  const size_t base = ((size_t)zz * M_REG + (size_t)bt * SEQ_) * C_ + d0;
  #pragma unroll
  for (int s = 0; s < SEQ_; s++) {
    const u16x8 vv = *(const u16x8*)&ypre[base + (size_t)s*C_];
    #pragma unroll
    for (int j = 0; j < 8; j++)
      accv[j] += fmaxf(sc[j] * bf2f(vv[j]) + sh[j], 0.f);
  }
  u16x8 ov;
  #pragma unroll
  for (int j = 0; j < 8; j++) ov[j] = f2bf(accv[j] * (1.f/21.f));
  *(u16x8*)&fv[((size_t)bt * NC_ + n) * C_ + d0] = ov;
}

__global__ __launch_bounds__(256)
void gat_k(const u16* __restrict__ hg, const u16* __restrict__ fv,
           const void* __restrict__ al, const void* __restrict__ ar,
           const void* __restrict__ adj_mask, u16* __restrict__ g,
           const int* __restrict__ flagp) {
  const int f32 = *flagp;
  const int bt = blockIdx.x;
  __shared__ float hl[12][512];
  __shared__ float alv[12], arv[12], attn[12][12];
  const u16* hgb = hg + (size_t)bt * NC_ * C_;
  for (int i = threadIdx.x * 8; i < 6144; i += 2048) {
    const u16x8 vv = *(const u16x8*)&hgb[i];
    const int ii = i >> 9, cc = i & 511;
    #pragma unroll
    for (int e = 0; e < 8; e++) hl[ii][cc + e] = bf2f(vv[e]);
  }
  __syncthreads();
  const int w = threadIdx.x >> 6, lane = threadIdx.x & 63;
  for (int i = w; i < 12; i += 4) {
    float pa = 0.f, pr = 0.f;
    #pragma unroll
    for (int jj = 0; jj < 8; jj++) {
      const int c = lane*8 + jj;
      const float hv = hl[i][c];
      pa += hv * ldf(al, c, f32);
      pr += hv * ldf(ar, c, f32);
    }
    #pragma unroll
    for (int off = 32; off; off >>= 1) { pa += __shfl_xor(pa, off); pr += __shfl_xor(pr, off); }
    if (lane == 0) { alv[i] = pa; arv[i] = pr; }
  }
  __syncthreads();
  if (threadIdx.x < 12) {
    const unsigned AM[12] = {0xFE8,0xFE8,0xFE8,0xFF7,0xFE8,0x1DF,
                             0xE3F,0xE3F,0xE3F,0x1DF,0x1DF,0x1DF};
    const int i = threadIdx.x;
    float row[12]; float mx = -1e30f;
    #pragma unroll
    for (int jx = 0; jx < 12; jx++) {
      const float maskv = ldf(adj_mask, (size_t)bt*144 + i*12 + jx, f32);
      const float adjv = (float)((AM[i] >> jx) & 1u) * maskv + (i == jx ? 1.f : 0.f);
      float e;
      if (adjv > 0.1f) {
        const float t = alv[i] + arv[jx];
        e = t > 0.f ? t : 0.2f * t;
      } else e = -1e9f;
      row[jx] = e; mx = fmaxf(mx, e);
    }
    float den = 0.f;
    #pragma unroll
    for (int jx = 0; jx < 12; jx++) { const float ex = __expf(row[jx] - mx); row[jx] = ex; den += ex; }
    const float inv = 1.f / den;
    #pragma unroll
    for (int jx = 0; jx < 12; jx++) attn[i][jx] = row[jx] * inv;
  }
  __syncthreads();
  const u16* fvb = fv + (size_t)bt * NC_ * C_;
  u16* gb = g + (size_t)bt * NC_ * C_;
  for (int o = threadIdx.x; o < 6144; o += 256) {
    const int i = o >> 9, c = o & 511;
    float acc = bf2f(fvb[o]);
    #pragma unroll
    for (int jx = 0; jx < 12; jx++) acc += attn[i][jx] * hl[jx][c];
    gb[o] = f2bf(acc);
  }
}

// ---- temporal depthwise conv (k=5, pad=2), in-place on bf16 g + stats ----
__global__ void tconv_k(u16* __restrict__ g, const void* __restrict__ tw,
                        const void* __restrict__ tb, float* __restrict__ tsum,
                        float* __restrict__ tsq, const int* __restrict__ flagp) {
  const int f32 = *flagp;
  const int id = blockIdx.x * 256 + threadIdx.x;
  const int c = id & 511;
  const int n = (id >> 9) % 12;
  const int b = id / 6144;
  float wk[5];
  #pragma unroll
  for (int k = 0; k < 5; k++) wk[k] = ldf(tw, (size_t)(n*512 + c)*5 + k, f32);
  const float bias = ldf(tb, n*512 + c, f32);
  float xv[36];
  xv[0] = xv[1] = xv[34] = xv[35] = 0.f;
  const size_t base = ((size_t)b * 32 * NC_ + n) * C_ + c;
  #pragma unroll
  for (int t = 0; t < 32; t++) xv[t + 2] = bf2f(g[base + (size_t)t * 6144]);
  float s = 0.f, s2 = 0.f;
  float ov[32];
  #pragma unroll
  for (int t = 0; t < 32; t++) {
    float v = bias;
    #pragma unroll
    for (int k = 0; k < 5; k++) v += wk[k] * xv[t + k];
    ov[t] = v; s += v; s2 += v*v;
  }
  #pragma unroll
  for (int t = 0; t < 32; t++) g[base + (size_t)t * 6144] = f2bf(ov[t]);
  #pragma unroll
  for (int off = 32; off; off >>= 1) { s += __shfl_xor(s, off); s2 += __shfl_xor(s2, off); }
  if ((threadIdx.x & 63) == 0) { atomicAdd(&tsum[n], s); atomicAdd(&tsq[n], s2); }
}

// ---- final BN+relu -> d_out; 8 elems/thread ----
__global__ void bn_t(const u16* __restrict__ v, void* __restrict__ outp,
                     const void* __restrict__ tg, const void* __restrict__ tb2,
                     const float* __restrict__ tsum, const float* __restrict__ tsq,
                     const int* __restrict__ flagp) {
  const int f32 = *flagp;
  const size_t id8 = (size_t)blockIdx.x * 256 + threadIdx.x;   // 786432 groups of 8
  const int n = (int)((id8 >> 6) % 12);
  const float mean = tsum[n] * (1.f/524288.f);
  const float var  = fmaxf(tsq[n] * (1.f/524288.f) - mean*mean, 0.f);
  const float sc = ldf(tg, n, f32) * rsqrtf(var + 1e-5f);
  const float sh = ldf(tb2, n, f32) - mean * sc;
  const u16x8 vv = *(const u16x8*)&v[id8 * 8];
  if (f32) {
    floatx4 o0, o1;
    #pragma unroll
    for (int e = 0; e < 4; e++) {
      o0[e] = fmaxf(sc * bf2f(vv[e])   + sh, 0.f);
      o1[e] = fmaxf(sc * bf2f(vv[4+e]) + sh, 0.f);
    }
    *(floatx4*)&((float*)outp)[43008 + id8*8]     = o0;
    *(floatx4*)&((float*)outp)[43008 + id8*8 + 4] = o1;
  } else {
    u16x8 ov;
    #pragma unroll
    for (int e = 0; e < 8; e++) ov[e] = f2bf(fmaxf(sc * bf2f(vv[e]) + sh, 0.f));
    *(u16x8*)&((u16*)outp)[43008 + id8*8] = ov;
  }
}

static constexpr size_t OFF_FLAG = 0;
static constexpr size_t OFF_STAT = 64;
static constexpr int    STAT_N   = 2048+2048+6144+6144+12+12;
static constexpr size_t OFF_WTR  = 65792;
static constexpr size_t OFF_WTC  = OFF_WTR + (size_t)4*512*512*2;
static constexpr size_t OFF_WTG  = OFF_WTC + (size_t)12*512*512*2;
static constexpr size_t OFF_H    = OFF_WTG + (size_t)512*512*2;
static constexpr size_t OFF_HBAR = OFF_H + (size_t)4*M_REG*C_*2;
static constexpr size_t OFF_FV   = OFF_HBAR + (size_t)4*BT_*C_*4;
static constexpr size_t OFF_AREN = OFF_FV + (size_t)M_GAT*C_*2;
static constexpr size_t YPRE_B   = (size_t)M_REG * C_ * 2;
static constexpr size_t NEEDED   = OFF_AREN + YPRE_B;

extern "C" void kernel_launch(void* const* d_in, const int* in_sizes, int n_in,
                              void* d_out, int out_size, void* d_ws, size_t ws_size,
                              hipStream_t stream) {
  const u16* x        = (const u16*)d_in[0];
  const void* adj_m   = d_in[1];
  const void* region_W= d_in[2];
  const void* region_b= d_in[3];
  const void* region_g= d_in[4];
  const void* region_be=d_in[5];
  const void* upW  = d_in[6];   const void* upB  = d_in[7];
  const void* midW = d_in[8];   const void* midB = d_in[9];
  const void* d1W  = d_in[10];  const void* d1B  = d_in[11];
  const void* d2W  = d_in[12];  const void* d2B  = d_in[13];
  const void* class_W = d_in[14];
  const void* class_b = d_in[15];
  const void* class_g = d_in[16];
  const void* class_be= d_in[17];
  const void* gat_W   = d_in[18];
  const void* gat_al  = d_in[19];
  const void* gat_ar  = d_in[20];
  const void* tconv_W = d_in[21];
  const void* tconv_b = d_in[22];
  const void* tbn_g   = d_in[23];
  const void* tbn_be  = d_in[24];

  char* ws = (char*)d_ws;
  int*   flagp = (int*)(ws + OFF_FLAG);
  float* rsum = (float*)(ws + OFF_STAT);
  float* rsq  = rsum + 2048;
  float* csum = rsq  + 2048;
  float* csq  = csum + 6144;
  float* tsum = csq  + 6144;
  float* tsq  = tsum + 12;
  u16*   WtR  = (u16*)(ws + OFF_WTR);
  u16*   WtC  = (u16*)(ws + OFF_WTC);
  u16*   WtG  = (u16*)(ws + OFF_WTG);
  u16*   h    = (u16*)(ws + OFF_H);
  float* hbar = (float*)(ws + OFF_HBAR);
  u16*   fv   = (u16*)(ws + OFF_FV);
  u16*   ypre = (u16*)(ws + OFF_AREN);
  u16*   hg   = (u16*)(ws + OFF_AREN);   // reuses ypre arena (class loop done)
  u16*   g    = (u16*)(ws + OFF_H);      // reuses h arena (class GEMMs done), bf16

  int errStage = 0, errCode = 0;
  (void)hipGetLastError();
  #define CK(s) do { hipError_t e_ = hipGetLastError(); \
      if (e_ != hipSuccess && errStage == 0) { errStage = (s); errCode = (int)e_; } } while(0)

  if (ws_size < NEEDED) {
    int mb = (int)(ws_size >> 20); if (mb > 999) mb = 999;
    sent_k<<<64, 256, 0, stream>>>((float*)d_out, 13000.f + (float)mb);
    return;
  }

  int nch = (int)((ws_size - OFF_AREN) / YPRE_B);
  if (nch > 12) nch = 12;
  if (nch < 1) nch = 1;

  const int ROFFPACK = 0 | (14 << 8) | (28 << 16) | (28 << 24);
  const int SELPACK  = (1 << 6) | (3 << 10) | (2 << 12) | (2 << 14) |
                       (2 << 16) | (3 << 18) | (3 << 20) | (3 << 22);

  detect_k<<<1 + (STAT_N + 255)/256, 256, 0, stream>>>(x, flagp, rsum, STAT_N); CK(1);
  transpose512<<<dim3(16,16,17), dim3(32,8), 0, stream>>>(
      region_W, class_W, gat_W, WtR, WtC, WtG, flagp);               CK(2);

  gemm_k<0><<<dim3(672,1,4), 256, 0, stream>>>(
      x, WtR, region_b, h, rsum, rsq, flagp, ROFFPACK, 0);           CK(3);
  bn_region<<<1024, 256, 0, stream>>>(h, hbar, region_g, region_be,
      rsum, rsq, flagp);                                             CK(4);
  preds_k<<<1024, 256, 0, stream>>>(hbar, upW,upB, midW,midB,
      d1W,d1B, d2W,d2B, d_out, flagp);                               CK(5);

  for (int n0 = 0; n0 < 12; n0 += nch) {
    const int zc = (12 - n0) < nch ? (12 - n0) : nch;
    gemm_k<1><<<dim3(672,1,zc), 256, 0, stream>>>(
        h, WtC, class_b, ypre, csum, csq, flagp, SELPACK, n0);       CK(6);
    bn_class_mean<<<zc*256, 256, 0, stream>>>(ypre, fv, class_g, class_be,
        csum, csq, flagp, n0);                                       CK(7);
  }

  gemm_k<2><<<dim3(384,1,1), 256, 0, stream>>>(
      fv, WtG, nullptr, hg, nullptr, nullptr, flagp, 0, 0);          CK(8);
  gat_k<<<1024, 256, 0, stream>>>(hg, fv, gat_al, gat_ar, adj_m, g, flagp); CK(9);
  tconv_k<<<768, 256, 0, stream>>>(g, tconv_W, tconv_b, tsum, tsq, flagp);  CK(10);
  bn_t<<<3072, 256, 0, stream>>>(g, d_out, tbn_g, tbn_be, tsum, tsq, flagp); CK(11);

  if (errStage) {
    int ec = errCode > 999 ? 999 : errCode;
    sent_k<<<64, 256, 0, stream>>>((float*)d_out, (float)(errStage*1000 + ec));
  }
  #undef CK
}